// Round 6
// baseline (35.538 us; speedup 1.0000x reference)
//
#include <hip/hip_runtime.h>
#include <math.h>

#define TAIL_B 20.0f
#define GI 512              // G * I = 8 * 64
#define BATCH 16384
#define NELEM (BATCH * GI)  // 8,388,608 elements per output tensor
#define ROWS_PB 64          // batch rows per main-kernel block

typedef float vf4 __attribute__((ext_vector_type(4)));

// Per-g workspace image (float offsets):
//   coarse [3][64]             @ 0    knot4/knot8/knot12, transposed (reg-loaded)
//   fine   [4][3][64] c-pad200 @ 192  knots 4c+1..4c+3; addr = c*200 + jp*64 + il
//   rec    [64][16] vf4        @ 992  (ch0, h, d0, d1) at slot k ^ ((il>>2)&7)
// GSTRIDE = 192 + 800 + 4096 = 5088 floats; ws = 8*5088*4 = 162,816 B
#define OFF_COARSE 0
#define OFF_FINE   192
#define OFF_REC    992
#define GSTRIDE    5088
#define LDS_FLOATS 4896     // fine(800) + rec(4096) = 19,584 B -> 8 blocks/CU

__global__ __launch_bounds__(256) void rqs_precompute(
    const float* __restrict__ W, const float* __restrict__ H,
    const float* __restrict__ D, float* __restrict__ ws)
{
    int gi = blockIdx.x * 256 + threadIdx.x;
    if (gi >= GI) return;
    int g = gi >> 6, il = gi & 63;
    int m7 = (il >> 2) & 7;

    float* base = ws + g * GSTRIDE;
    vf4*   rec  = reinterpret_cast<vf4*>(base + OFF_REC);

    const float* Wg = W + gi * 16;
    const float* Hg = H + gi * 16;
    const float* Dg = D + gi * 15;

    float mw = Wg[0], mh = Hg[0];
#pragma unroll
    for (int k = 1; k < 16; ++k) { mw = fmaxf(mw, Wg[k]); mh = fmaxf(mh, Hg[k]); }
    float sumw = 0.0f, sumh = 0.0f;
#pragma unroll
    for (int k = 0; k < 16; ++k) { sumw += expf(Wg[k] - mw); sumh += expf(Hg[k] - mh); }
    float scw = (2.0f * TAIL_B) / sumw;
    float sch = (2.0f * TAIL_B) / sumh;

    float cw = -TAIL_B, ch = -TAIL_B, dprev = 1.0f;
#pragma unroll
    for (int k = 0; k < 16; ++k) {
        float wk = expf(Wg[k] - mw) * scw;
        float hk = expf(Hg[k] - mh) * sch;
        float dnext = 1.0f;
        if (k < 15) {
            float v = Dg[k];
            dnext = fmaxf(v, 0.0f) + log1pf(expf(-fabsf(v)));  // stable softplus
        }
        rec[il * 16 + (k ^ m7)] = (vf4){ch, hk, dprev, dnext};
        cw += wk; ch += hk; dprev = dnext;
        int t = k + 1;                    // right-edge knot index
        if (t < 16) {
            if ((t & 3) == 0) base[OFF_COARSE + ((t >> 2) - 1) * 64 + il] = cw;
            else              base[OFF_FINE + (t >> 2) * 200 + ((t & 3) - 1) * 64 + il] = cw;
        }
    }
}

__global__ __launch_bounds__(256, 8) void rqs_main(
    const float* __restrict__ x, const float* __restrict__ ws,
    float* __restrict__ out)
{
    __shared__ float s_tab[LDS_FLOATS];   // 19,584 B

    int g     = blockIdx.x & 7;
    int chunk = blockIdx.x >> 3;
    int tid   = threadIdx.x;

    int icol = (tid * 4) & 63;        // 4 columns, constant across r
    int row0 = tid >> 4;              // 0..15
    int m7   = (icol >> 2) & 7;       // same for all j (icol%4==0, j<4)
    int base = chunk * (ROWS_PB * 512) + g * 64;

    // issue x loads early (overlap with staging)
    vf4 xv0 = *reinterpret_cast<const vf4*>(x + base + (row0     ) * 512 + icol);
    vf4 xv1 = *reinterpret_cast<const vf4*>(x + base + (row0 + 16) * 512 + icol);
    vf4 xv2 = *reinterpret_cast<const vf4*>(x + base + (row0 + 32) * 512 + icol);
    vf4 xv3 = *reinterpret_cast<const vf4*>(x + base + (row0 + 48) * 512 + icol);

    // coarse knots -> registers
    const float* cb = ws + g * GSTRIDE + OFF_COARSE;
    vf4 ck4  = *reinterpret_cast<const vf4*>(cb + icol);
    vf4 ck8  = *reinterpret_cast<const vf4*>(cb + 64 + icol);
    vf4 ck12 = *reinterpret_cast<const vf4*>(cb + 128 + icol);

    // stage fine+rec image (coalesced, pre-swizzled, no math)
    {
        const vf4* src = reinterpret_cast<const vf4*>(ws + g * GSTRIDE + OFF_FINE);
        vf4*       dst = reinterpret_cast<vf4*>(s_tab);
#pragma unroll
        for (int i = 0; i < 5; ++i) {
            int t4 = tid + 256 * i;
            if (t4 < LDS_FLOATS / 4) dst[t4] = src[t4];
        }
    }
    __syncthreads();

    const vf4* s_rec = reinterpret_cast<const vf4*>(s_tab + 800);

#pragma unroll
    for (int r = 0; r < 4; ++r) {
        vf4 xq = (r == 0) ? xv0 : (r == 1) ? xv1 : (r == 2) ? xv2 : xv3;
        float zs[4], ls[4];

#pragma unroll
        for (int j = 0; j < 4; ++j) {
            int   il = icol + j;
            float xx = xq[j];
            bool  inside = (xx >= -TAIL_B) && (xx <= TAIL_B);
            float xc = fminf(fmaxf(xx, -TAIL_B), TAIL_B);

            // coarse level: registers only
            bool b1 = xc >= ck4[j], b2 = xc >= ck8[j], b3 = xc >= ck12[j];
            int  c  = (int)b1 + (int)b2 + (int)b3;
            float kb = b3 ? ck12[j] : (b2 ? ck8[j] : (b1 ? ck4[j] : -TAIL_B)); // knot 4c
            float kt = b3 ? TAIL_B  : (b2 ? ck12[j] : (b1 ? ck8[j] : ck4[j])); // knot 4c+4

            // fine level: 3 parallel LDS reads, banks (il + 8c) % 32
            const float* kp = s_tab + c * 200 + il;
            float f0 = kp[0], f1 = kp[64], f2 = kp[128];
            bool a1 = xc >= f0, a2 = xc >= f1, a3 = xc >= f2;
            int  idx = 4 * c + (int)a1 + (int)a2 + (int)a3;
            float k0 = a3 ? f2 : (a2 ? f1 : (a1 ? f0 : kb));
            float k1 = a3 ? kt : (a2 ? f2 : (a1 ? f1 : f0));

            vf4 rc = s_rec[il * 16 + (idx ^ m7)];     // ch0, h, d0, d1

            float invw  = __builtin_amdgcn_rcpf(k1 - k0);
            float hh    = rc.y;
            float de    = hh * invw;
            float theta = (xc - k0) * invw;
            float omt   = 1.0f - theta;
            float tt    = theta * omt;
            float denom = de + (rc.z + rc.w - 2.0f * de) * tt;
            float rden  = __builtin_amdgcn_rcpf(denom);
            float numer = hh * (de * theta * theta + rc.z * tt);
            float zin   = rc.x + numer * rden;
            float dnum  = de * de * (rc.w * theta * theta + 2.0f * de * tt + rc.z * omt * omt);
            float ldin  = 0.6931471805599453f * __log2f(dnum * rden * rden);

            zs[j] = inside ? zin : xx;
            ls[j] = inside ? ldin : 0.0f;
        }

        int addr = base + (row0 + r * 16) * 512 + icol;
        vf4 zq = {zs[0], zs[1], zs[2], zs[3]};
        vf4 lq = {ls[0], ls[1], ls[2], ls[3]};
        __builtin_nontemporal_store(zq, reinterpret_cast<vf4*>(out + addr));
        __builtin_nontemporal_store(lq, reinterpret_cast<vf4*>(out + NELEM + addr));
    }
}

extern "C" void kernel_launch(void* const* d_in, const int* in_sizes, int n_in,
                              void* d_out, int out_size, void* d_ws, size_t ws_size,
                              hipStream_t stream)
{
    const float* x = (const float*)d_in[0];
    const float* W = (const float*)d_in[1];
    const float* H = (const float*)d_in[2];
    const float* D = (const float*)d_in[3];
    float* out = (float*)d_out;
    float* ws  = (float*)d_ws;

    rqs_precompute<<<GI / 256, 256, 0, stream>>>(W, H, D, ws);

    int nblocks = 8 * (BATCH / ROWS_PB);   // 2048 = exactly 8 blocks/CU * 256 CU
    rqs_main<<<nblocks, 256, 0, stream>>>(x, ws, out);
}

// Round 7
// 33.642 us; speedup vs baseline: 1.0564x; 1.0564x over previous
//
#include <hip/hip_runtime.h>
#include <math.h>

#define TAIL_B 20.0f
#define GI 512              // G * I = 8 * 64
#define BATCH 16384
#define NELEM (BATCH * GI)  // 8,388,608 elements per output tensor
#define ROWS_PB 128         // batch rows per main-kernel block

typedef float vf4 __attribute__((ext_vector_type(4)));

// Per-g workspace image (float offsets):
//   knotT [15][64] @ 0     interior knots 1..15, transposed (reg-loaded per lane)
//   cumw  [64][17] @ 960   knot x, stride 17 (odd -> conflict-free lane=il gathers)
//   cumh  [64][17] @ 2048
//   dk    [64][17] @ 3136  derivatives at knots, dk[0]=dk[16]=1
#define G_KNT 0
#define G_CW  960
#define G_CH  2048
#define G_DK  3136
#define GSTRIDE 4224        // floats per g; ws total 8*4224*4 = 135,168 B
#define LDSF 3264           // cumw+cumh+dk = 13,056 B

__global__ __launch_bounds__(256) void rqs_precompute(
    const float* __restrict__ W, const float* __restrict__ H,
    const float* __restrict__ D, float* __restrict__ ws)
{
    int gi = blockIdx.x * 256 + threadIdx.x;
    if (gi >= GI) return;
    int g = gi >> 6, il = gi & 63;
    float* bg = ws + g * GSTRIDE;

    const float* Wg = W + gi * 16;
    const float* Hg = H + gi * 16;
    const float* Dg = D + gi * 15;

    float mw = Wg[0], mh = Hg[0];
#pragma unroll
    for (int k = 1; k < 16; ++k) { mw = fmaxf(mw, Wg[k]); mh = fmaxf(mh, Hg[k]); }
    float sumw = 0.0f, sumh = 0.0f;
#pragma unroll
    for (int k = 0; k < 16; ++k) { sumw += expf(Wg[k] - mw); sumh += expf(Hg[k] - mh); }
    float scw = (2.0f * TAIL_B) / sumw;
    float sch = (2.0f * TAIL_B) / sumh;

    bg[G_CW + il * 17] = -TAIL_B;
    bg[G_CH + il * 17] = -TAIL_B;
    bg[G_DK + il * 17] = 1.0f;

    float cw = -TAIL_B, ch = -TAIL_B;
#pragma unroll
    for (int k = 0; k < 16; ++k) {
        float wk = expf(Wg[k] - mw) * scw;
        float hk = expf(Hg[k] - mh) * sch;
        cw += wk; ch += hk;
        float dnext = 1.0f;
        if (k < 15) {
            float v = Dg[k];
            dnext = fmaxf(v, 0.0f) + log1pf(expf(-fabsf(v)));  // stable softplus
        }
        bg[G_CW + il * 17 + k + 1] = cw;
        bg[G_CH + il * 17 + k + 1] = ch;
        bg[G_DK + il * 17 + k + 1] = dnext;
        if (k < 15) bg[G_KNT + k * 64 + il] = cw;   // interior knot k+1
    }
}

__global__ __launch_bounds__(256, 4) void rqs_main(
    const float* __restrict__ x, const float* __restrict__ ws,
    float* __restrict__ out)
{
    __shared__ float s[LDSF];   // cumw @0, cumh @1088, dk @2176

    int g     = blockIdx.x & 7;
    int chunk = blockIdx.x >> 3;
    int lane  = threadIdx.x & 63;
    int wsub  = threadIdx.x >> 6;      // 0..3

    const float* bg = ws + g * GSTRIDE;

    // stage stride-17 tables (coalesced vf4)
    {
        const vf4* src = reinterpret_cast<const vf4*>(bg + G_CW);
        vf4*       dst = reinterpret_cast<vf4*>(s);
#pragma unroll
        for (int i = 0; i < 4; ++i) {
            int t = threadIdx.x + 256 * i;
            if (t < LDSF / 4) dst[t] = src[t];
        }
    }

    // 15 interior knots -> registers (compile-time indexed only)
    float kr[15];
#pragma unroll
    for (int t = 0; t < 15; ++t) kr[t] = bg[G_KNT + t * 64 + lane];

    __syncthreads();

    const float* sCW = s;
    const float* sCH = s + 1088;
    const float* sDK = s + 2176;

    int colbase = g * 64 + lane;
    int rowbase = chunk * ROWS_PB + wsub;   // this thread's rows: rowbase + 4*i

#pragma unroll
    for (int b = 0; b < 4; ++b) {
        float xb[8];
#pragma unroll
        for (int i = 0; i < 8; ++i)
            xb[i] = x[(size_t)(rowbase + (b * 8 + i) * 4) * 512 + colbase];

#pragma unroll
        for (int i = 0; i < 8; ++i) {
            float xx = xb[i];
            bool  inside = (xx >= -TAIL_B) && (xx <= TAIL_B);
            float xc = fminf(fmaxf(xx, -TAIL_B), TAIL_B);

            // register-resident bin search: idx = #knots <= xc
            int idx = 0;
#pragma unroll
            for (int t = 0; t < 15; ++t) idx += (xc >= kr[t]) ? 1 : 0;

            int p = lane * 17 + idx;
            float k0  = sCW[p], k1  = sCW[p + 1];
            float ch0 = sCH[p], ch1 = sCH[p + 1];
            float d0  = sDK[p], d1  = sDK[p + 1];

            float invw  = __builtin_amdgcn_rcpf(k1 - k0);
            float hh    = ch1 - ch0;
            float de    = hh * invw;
            float theta = (xc - k0) * invw;
            float omt   = 1.0f - theta;
            float tt    = theta * omt;
            float denom = de + (d0 + d1 - 2.0f * de) * tt;
            float rden  = __builtin_amdgcn_rcpf(denom);
            float numer = hh * (de * theta * theta + d0 * tt);
            float zin   = ch0 + numer * rden;
            float dnum  = de * de * (d1 * theta * theta + 2.0f * de * tt + d0 * omt * omt);
            float ldin  = 0.6931471805599453f * __log2f(dnum * rden * rden);

            float z  = inside ? zin : xx;
            float ld = inside ? ldin : 0.0f;

            size_t addr = (size_t)(rowbase + (b * 8 + i) * 4) * 512 + colbase;
            __builtin_nontemporal_store(z,  out + addr);
            __builtin_nontemporal_store(ld, out + NELEM + addr);
        }
    }
}

extern "C" void kernel_launch(void* const* d_in, const int* in_sizes, int n_in,
                              void* d_out, int out_size, void* d_ws, size_t ws_size,
                              hipStream_t stream)
{
    const float* x = (const float*)d_in[0];
    const float* W = (const float*)d_in[1];
    const float* H = (const float*)d_in[2];
    const float* D = (const float*)d_in[3];
    float* out = (float*)d_out;
    float* ws  = (float*)d_ws;

    rqs_precompute<<<GI / 256, 256, 0, stream>>>(W, H, D, ws);

    int nblocks = 8 * (BATCH / ROWS_PB);   // 1024 = exactly 4 blocks/CU
    rqs_main<<<nblocks, 256, 0, stream>>>(x, ws, out);
}

// Round 8
// 31.926 us; speedup vs baseline: 1.1131x; 1.0537x over previous
//
#include <hip/hip_runtime.h>
#include <math.h>

#define TAIL_B 20.0f
#define GI 512              // G * I = 8 * 64
#define BATCH 16384
#define NELEM (BATCH * GI)  // 8,388,608 elements per output tensor
#define ROWS_PB 64          // batch rows per main-kernel block

typedef float vf4 __attribute__((ext_vector_type(4)));

// Per-g workspace image (float offsets):
//   knotT [15][64] @ 0     interior knots 1..15, transposed (reg-loaded per lane)
//   cumw  [64][17] @ 960   knot x, stride 17 (odd -> conflict-free lane=il gathers)
//   cumh  [64][17] @ 2048
//   dk    [64][17] @ 3136  derivatives at knots, dk[0]=dk[16]=1
#define G_KNT 0
#define G_CW  960
#define G_CH  2048
#define G_DK  3136
#define GSTRIDE 4224        // floats per g; ws total 8*4224*4 = 135,168 B
#define LDSF 3264           // cumw+cumh+dk = 13,056 B -> 8 blocks/CU

__global__ __launch_bounds__(256) void rqs_precompute(
    const float* __restrict__ W, const float* __restrict__ H,
    const float* __restrict__ D, float* __restrict__ ws)
{
    int gi = blockIdx.x * 256 + threadIdx.x;
    if (gi >= GI) return;
    int g = gi >> 6, il = gi & 63;
    float* bg = ws + g * GSTRIDE;

    const float* Wg = W + gi * 16;
    const float* Hg = H + gi * 16;
    const float* Dg = D + gi * 15;

    float mw = Wg[0], mh = Hg[0];
#pragma unroll
    for (int k = 1; k < 16; ++k) { mw = fmaxf(mw, Wg[k]); mh = fmaxf(mh, Hg[k]); }
    float sumw = 0.0f, sumh = 0.0f;
#pragma unroll
    for (int k = 0; k < 16; ++k) { sumw += expf(Wg[k] - mw); sumh += expf(Hg[k] - mh); }
    float scw = (2.0f * TAIL_B) / sumw;
    float sch = (2.0f * TAIL_B) / sumh;

    bg[G_CW + il * 17] = -TAIL_B;
    bg[G_CH + il * 17] = -TAIL_B;
    bg[G_DK + il * 17] = 1.0f;

    float cw = -TAIL_B, ch = -TAIL_B;
#pragma unroll
    for (int k = 0; k < 16; ++k) {
        float wk = expf(Wg[k] - mw) * scw;
        float hk = expf(Hg[k] - mh) * sch;
        cw += wk; ch += hk;
        float dnext = 1.0f;
        if (k < 15) {
            float v = Dg[k];
            dnext = fmaxf(v, 0.0f) + log1pf(expf(-fabsf(v)));  // stable softplus
        }
        bg[G_CW + il * 17 + k + 1] = cw;
        bg[G_CH + il * 17 + k + 1] = ch;
        bg[G_DK + il * 17 + k + 1] = dnext;
        if (k < 15) bg[G_KNT + k * 64 + il] = cw;   // interior knot k+1
    }
}

__global__ __launch_bounds__(256, 8) void rqs_main(
    const float* __restrict__ x, const float* __restrict__ ws,
    float* __restrict__ out)
{
    __shared__ float s[LDSF];   // cumw @0, cumh @1088, dk @2176

    int g     = blockIdx.x & 7;
    int chunk = blockIdx.x >> 3;
    int lane  = threadIdx.x & 63;
    int wsub  = threadIdx.x >> 6;      // 0..3

    const float* bg = ws + g * GSTRIDE;

    int colbase = g * 64 + lane;
    int rowbase = chunk * ROWS_PB + wsub;   // this thread's rows: rowbase + 4*i

    // issue ALL 16 x loads upfront (max memory-level parallelism)
    float xb[16];
#pragma unroll
    for (int i = 0; i < 16; ++i)
        xb[i] = x[(rowbase + i * 4) * 512 + colbase];

    // stage stride-17 tables (coalesced vf4)
    {
        const vf4* src = reinterpret_cast<const vf4*>(bg + G_CW);
        vf4*       dst = reinterpret_cast<vf4*>(s);
#pragma unroll
        for (int i = 0; i < 4; ++i) {
            int t = threadIdx.x + 256 * i;
            if (t < LDSF / 4) dst[t] = src[t];
        }
    }

    // 15 interior knots -> registers (compile-time indexed only)
    float kr[15];
#pragma unroll
    for (int t = 0; t < 15; ++t) kr[t] = bg[G_KNT + t * 64 + lane];

    __syncthreads();

    const float* sCW = s;
    const float* sCH = s + 1088;
    const float* sDK = s + 2176;

#pragma unroll
    for (int i = 0; i < 16; ++i) {
        float xx = xb[i];
        bool  inside = (xx >= -TAIL_B) && (xx <= TAIL_B);
        float xc = fminf(fmaxf(xx, -TAIL_B), TAIL_B);

        // register-resident bin search: idx = #knots <= xc
        int idx = 0;
#pragma unroll
        for (int t = 0; t < 15; ++t) idx += (xc >= kr[t]) ? 1 : 0;

        int p = lane * 17 + idx;
        float k0  = sCW[p], k1  = sCW[p + 1];
        float ch0 = sCH[p], ch1 = sCH[p + 1];
        float d0  = sDK[p], d1  = sDK[p + 1];

        float invw  = __builtin_amdgcn_rcpf(k1 - k0);
        float hh    = ch1 - ch0;
        float de    = hh * invw;
        float theta = (xc - k0) * invw;
        float omt   = 1.0f - theta;
        float tt    = theta * omt;
        float denom = de + (d0 + d1 - 2.0f * de) * tt;
        float rden  = __builtin_amdgcn_rcpf(denom);
        float numer = hh * (de * theta * theta + d0 * tt);
        float zin   = ch0 + numer * rden;
        float dnum  = de * de * (d1 * theta * theta + 2.0f * de * tt + d0 * omt * omt);
        float ldin  = 0.6931471805599453f * __log2f(dnum * rden * rden);

        float z  = inside ? zin : xx;
        float ld = inside ? ldin : 0.0f;

        int addr = (rowbase + i * 4) * 512 + colbase;
        __builtin_nontemporal_store(z,  out + addr);
        __builtin_nontemporal_store(ld, out + NELEM + addr);
    }
}

extern "C" void kernel_launch(void* const* d_in, const int* in_sizes, int n_in,
                              void* d_out, int out_size, void* d_ws, size_t ws_size,
                              hipStream_t stream)
{
    const float* x = (const float*)d_in[0];
    const float* W = (const float*)d_in[1];
    const float* H = (const float*)d_in[2];
    const float* D = (const float*)d_in[3];
    float* out = (float*)d_out;
    float* ws  = (float*)d_ws;

    rqs_precompute<<<GI / 256, 256, 0, stream>>>(W, H, D, ws);

    int nblocks = 8 * (BATCH / ROWS_PB);   // 2048 = exactly 8 blocks/CU
    rqs_main<<<nblocks, 256, 0, stream>>>(x, ws, out);
}

// Round 9
// 30.992 us; speedup vs baseline: 1.1467x; 1.0301x over previous
//
#include <hip/hip_runtime.h>
#include <math.h>

#define TAIL_B 20.0f
#define GI 512              // G * I = 8 * 64
#define BATCH 16384
#define NELEM (BATCH * GI)  // 8,388,608 elements per output tensor
#define ROWS_PB 64          // batch rows per block

typedef float vf4 __attribute__((ext_vector_type(4)));

// LDS tables (float offsets), stride 17 (odd -> conflict-free lane=il gathers):
//   cumw [64][17] @ 0      knot x
//   cumh [64][17] @ 1088   knot y
//   dk   [64][17] @ 2176   derivatives at knots, dk[0]=dk[16]=1
#define LDSF 3264           // 13,056 B -> 8 blocks/CU

__global__ __launch_bounds__(256, 8) void rqs_fused(
    const float* __restrict__ x, const float* __restrict__ W,
    const float* __restrict__ H, const float* __restrict__ D,
    float* __restrict__ out)
{
    __shared__ float s[LDSF];

    int tid   = threadIdx.x;
    int g     = blockIdx.x & 7;
    int chunk = blockIdx.x >> 3;
    int lane  = tid & 63;
    int wsub  = tid >> 6;            // 0..3

    int colbase = g * 64 + lane;
    int rowbase = chunk * ROWS_PB + wsub;

    // ---- prefetch ALL 16 x values (independent of prologue; hides under it) ----
    float xb[16];
#pragma unroll
    for (int i = 0; i < 16; ++i)
        xb[i] = x[(rowbase + i * 4) * 512 + colbase];

    // ---- cooperative table build: 4 threads per column (quad-lane aligned) ----
    {
        int col = tid >> 2;          // 0..63 (same for the 4 quad lanes)
        int kp  = tid & 3;           // this thread's bins: 4kp..4kp+3
        int gi  = g * 64 + col;
        int qb  = lane & ~3;         // quad base lane

        vf4 wv = *reinterpret_cast<const vf4*>(W + gi * 16 + kp * 4);
        vf4 hv = *reinterpret_cast<const vf4*>(H + gi * 16 + kp * 4);

        float mw = fmaxf(fmaxf(wv.x, wv.y), fmaxf(wv.z, wv.w));
        float mh = fmaxf(fmaxf(hv.x, hv.y), fmaxf(hv.z, hv.w));
        mw = fmaxf(mw, __shfl_xor(mw, 1)); mw = fmaxf(mw, __shfl_xor(mw, 2));
        mh = fmaxf(mh, __shfl_xor(mh, 1)); mh = fmaxf(mh, __shfl_xor(mh, 2));

        float w0 = expf(wv.x - mw), w1 = expf(wv.y - mw),
              w2 = expf(wv.z - mw), w3 = expf(wv.w - mw);
        float h0 = expf(hv.x - mh), h1 = expf(hv.y - mh),
              h2 = expf(hv.z - mh), h3 = expf(hv.w - mh);
        float Tw = w0 + w1 + w2 + w3;
        float Th = h0 + h1 + h2 + h3;

        float tw0 = __shfl(Tw, qb), tw1 = __shfl(Tw, qb + 1),
              tw2 = __shfl(Tw, qb + 2), tw3 = __shfl(Tw, qb + 3);
        float th0 = __shfl(Th, qb), th1 = __shfl(Th, qb + 1),
              th2 = __shfl(Th, qb + 2), th3 = __shfl(Th, qb + 3);
        float scw = (2.0f * TAIL_B) / (tw0 + tw1 + tw2 + tw3);
        float sch = (2.0f * TAIL_B) / (th0 + th1 + th2 + th3);
        float offw = (kp > 0 ? tw0 : 0.f) + (kp > 1 ? tw1 : 0.f) + (kp > 2 ? tw2 : 0.f);
        float offh = (kp > 0 ? th0 : 0.f) + (kp > 1 ? th1 : 0.f) + (kp > 2 ? th2 : 0.f);

        float cwb = -TAIL_B + offw * scw;     // cumw at knot 4kp
        float chb = -TAIL_B + offh * sch;

        float* sc = s + col * 17;
        sc[4 * kp + 1]        = cwb + w0 * scw;
        sc[4 * kp + 2]        = cwb + (w0 + w1) * scw;
        sc[4 * kp + 3]        = cwb + (w0 + w1 + w2) * scw;
        sc[4 * kp + 4]        = cwb + (w0 + w1 + w2 + w3) * scw;
        sc[1088 + 4 * kp + 1] = chb + h0 * sch;
        sc[1088 + 4 * kp + 2] = chb + (h0 + h1) * sch;
        sc[1088 + 4 * kp + 3] = chb + (h0 + h1 + h2) * sch;
        sc[1088 + 4 * kp + 4] = chb + (h0 + h1 + h2 + h3) * sch;

        // derivatives: dk[t] for t = 4kp+1 .. 4kp+4 ; D index t-1, knot16 -> 1
        const float* Dg = D + gi * 15;
#pragma unroll
        for (int j = 0; j < 4; ++j) {
            int t = 4 * kp + 1 + j;
            float dv = 1.0f;
            if (t < 16) {
                float v = Dg[t - 1];
                dv = fmaxf(v, 0.0f) + log1pf(expf(-fabsf(v)));  // stable softplus
            }
            sc[2176 + t] = dv;
        }
        if (kp == 0) {
            sc[0]    = -TAIL_B;
            sc[1088] = -TAIL_B;
            sc[2176] = 1.0f;
        }
    }
    __syncthreads();

    // 15 interior knots -> registers (conflict-free: bank = (17*lane + t) % 32)
    float kr[15];
#pragma unroll
    for (int t = 0; t < 15; ++t) kr[t] = s[lane * 17 + 1 + t];

    const float* sCW = s;
    const float* sCH = s + 1088;
    const float* sDK = s + 2176;

#pragma unroll
    for (int i = 0; i < 16; ++i) {
        float xx = xb[i];
        bool  inside = (xx >= -TAIL_B) && (xx <= TAIL_B);
        float xc = fminf(fmaxf(xx, -TAIL_B), TAIL_B);

        // register-resident bin search: idx = #knots <= xc
        int idx = 0;
#pragma unroll
        for (int t = 0; t < 15; ++t) idx += (xc >= kr[t]) ? 1 : 0;

        int p = lane * 17 + idx;
        float k0  = sCW[p], k1  = sCW[p + 1];
        float ch0 = sCH[p], ch1 = sCH[p + 1];
        float d0  = sDK[p], d1  = sDK[p + 1];

        float invw  = __builtin_amdgcn_rcpf(k1 - k0);
        float hh    = ch1 - ch0;
        float de    = hh * invw;
        float theta = (xc - k0) * invw;
        float omt   = 1.0f - theta;
        float tt    = theta * omt;
        float denom = de + (d0 + d1 - 2.0f * de) * tt;
        float rden  = __builtin_amdgcn_rcpf(denom);
        float numer = hh * (de * theta * theta + d0 * tt);
        float zin   = ch0 + numer * rden;
        float dnum  = de * de * (d1 * theta * theta + 2.0f * de * tt + d0 * omt * omt);
        float ldin  = 0.6931471805599453f * __log2f(dnum * rden * rden);

        float z  = inside ? zin : xx;
        float ld = inside ? ldin : 0.0f;

        int addr = (rowbase + i * 4) * 512 + colbase;
        __builtin_nontemporal_store(z,  out + addr);
        __builtin_nontemporal_store(ld, out + NELEM + addr);
    }
}

extern "C" void kernel_launch(void* const* d_in, const int* in_sizes, int n_in,
                              void* d_out, int out_size, void* d_ws, size_t ws_size,
                              hipStream_t stream)
{
    const float* x = (const float*)d_in[0];
    const float* W = (const float*)d_in[1];
    const float* H = (const float*)d_in[2];
    const float* D = (const float*)d_in[3];
    float* out = (float*)d_out;

    int nblocks = 8 * (BATCH / ROWS_PB);   // 2048 = exactly 8 blocks/CU
    rqs_fused<<<nblocks, 256, 0, stream>>>(x, W, H, D, out);
}